// Round 3
// baseline (509.358 us; speedup 1.0000x reference)
//
#include <hip/hip_runtime.h>
#include <math.h>

// Problem: emb lookup -> per-step RNN tanh(xp_t + h @ W_hh^T) over S=128 -> 5-class head.
// B=4096, S=128, D=256, VOCAB=50000.
// DTYPES (per harness contract, matching the reference): all float tensors are FLOAT32,
// x is int32, out is FLOAT32. (Rounds 1-2 NaN'd because f32 buffers were read as bf16:
// low half-words decode to bf16 with huge exponents -> MFMA inf-inf -> NaN.)
//
//  Phase 0: P[v][n] = sum_k emb[v][k]*W_ih[n][k] + b_ih[n] + b_hh[n]  — project the TABLE
//           (50000 rows, ~10x cheaper than projecting 524288 tokens). P stored bf16 in a
//           __device__ global (25.6 MB: fits aggregate L2, so phase-1 gathers are cheap).
//  Phase 1: 256 blocks x 16 batch rows; whole 128-step time loop in one kernel. W_hh cast
//           to bf16 MFMA B-fragments held in VGPRs; h round-trips LDS as bf16 (f32 accum
//           in MFMA); xp gathered from P with 1-step-ahead prefetch (double-buffered LDS).

typedef __attribute__((ext_vector_type(8))) short bf16x8;   // 8 bf16 = 4 VGPRs
typedef __attribute__((ext_vector_type(4))) float f32x4;    // MFMA 16x16 accumulator

#define LDS_STRIDE 264   // 256 + 8 pad (bf16 elems) to break LDS bank conflicts
#define VOCAB 50000

// Projected embedding table, 50000 x 256 bf16 = 25.6 MB. Module BSS; fully rewritten
// by phase 0 on every kernel_launch call (no cross-call state assumptions).
__device__ __align__(256) unsigned short g_P[VOCAB * 256];

static __device__ __forceinline__ float bf2f(unsigned short u) {
    union { unsigned int i; float f; } v; v.i = ((unsigned int)u) << 16; return v.f;
}
static __device__ __forceinline__ unsigned short f2bf(float f) {
    union { float f; unsigned int i; } v; v.f = f;
    unsigned int r = v.i + 0x7FFFu + ((v.i >> 16) & 1u);   // round-nearest-even
    return (unsigned short)(r >> 16);
}
// Pack 8 consecutive f32 -> bf16x8 fragment (RNE)
static __device__ __forceinline__ bf16x8 pack8(const float* __restrict__ p) {
    bf16x8 r;
    #pragma unroll
    for (int i = 0; i < 8; ++i) r[i] = (short)f2bf(p[i]);
    return r;
}

// ---------------- Phase 0: P = bf16(emb @ W_ih^T + (b_ih + b_hh)) ----------------
__global__ __launch_bounds__(256, 1)
void emb_proj_kernel(const float* __restrict__ emb,
                     const float* __restrict__ W_ih,
                     const float* __restrict__ b_ih,
                     const float* __restrict__ b_hh)
{
    __shared__ __align__(16) unsigned short tile[16 * LDS_STRIDE];
    const int tid  = threadIdx.x;
    const int lane = tid & 63;
    const int wid  = tid >> 6;          // 4 waves
    const int v0   = blockIdx.x * 16;   // 3125 * 16 == 50000 exactly
    const int n0   = wid * 64;          // wave's 64-col slice

    // W_ih (f32) -> bf16 B-fragments: B[k][n] = W_ih[n][k]; n = lane&15, k = quad*8 + j
    bf16x8 wf[4][8];
    #pragma unroll
    for (int nt = 0; nt < 4; ++nt) {
        int n = n0 + nt * 16 + (lane & 15);
        #pragma unroll
        for (int kt = 0; kt < 8; ++kt) {
            int k = (lane >> 4) * 8 + kt * 32;
            wf[nt][kt] = pack8(W_ih + n * 256 + k);
        }
    }

    // Stage 16 emb rows (f32 -> bf16) into LDS
    {
        int row = tid >> 4, seg = tid & 15;   // each thread: 16 f32 -> 16 bf16 (32B)
        const float* src = emb + (size_t)(v0 + row) * 256 + seg * 16;
        bf16x8 lo = pack8(src), hi = pack8(src + 8);
        *(bf16x8*)(&tile[row * LDS_STRIDE + seg * 16])     = lo;
        *(bf16x8*)(&tile[row * LDS_STRIDE + seg * 16 + 8]) = hi;
    }
    __syncthreads();

    f32x4 acc[4];
    #pragma unroll
    for (int nt = 0; nt < 4; ++nt) acc[nt] = (f32x4){0.f, 0.f, 0.f, 0.f};
    #pragma unroll
    for (int kt = 0; kt < 8; ++kt) {
        // A[m][k]: m = lane&15, k = (lane>>4)*8 + kt*32 + j
        bf16x8 a = *(bf16x8*)(&tile[(lane & 15) * LDS_STRIDE + (lane >> 4) * 8 + kt * 32]);
        #pragma unroll
        for (int nt = 0; nt < 4; ++nt)
            acc[nt] = __builtin_amdgcn_mfma_f32_16x16x32_bf16(a, wf[nt][kt], acc[nt], 0, 0, 0);
    }
    __syncthreads();   // all A reads done; reuse tile as output staging

    // C/D layout: col = lane&15, row = (lane>>4)*4 + r
    #pragma unroll
    for (int nt = 0; nt < 4; ++nt) {
        int n = n0 + nt * 16 + (lane & 15);
        float bias = b_ih[n] + b_hh[n];
        #pragma unroll
        for (int r = 0; r < 4; ++r) {
            int row = (lane >> 4) * 4 + r;
            tile[row * LDS_STRIDE + n] = f2bf(acc[nt][r] + bias);
        }
    }
    __syncthreads();
    {
        int row = tid >> 4, seg = tid & 15;
        float4 a0 = *(float4*)(&tile[row * LDS_STRIDE + seg * 16]);
        float4 a1 = *(float4*)(&tile[row * LDS_STRIDE + seg * 16 + 8]);
        float4* dst = (float4*)(g_P + (size_t)(v0 + row) * 256 + seg * 16);
        dst[0] = a0; dst[1] = a1;
    }
}

// ---------------- Phase 1: recurrence + classifier ----------------
__global__ __launch_bounds__(256, 1)
void rnn_kernel(const int* __restrict__ x,
                const float* __restrict__ W_hh,
                const float* __restrict__ W_cls,
                const float* __restrict__ b_cls,
                float* __restrict__ out)
{
    __shared__ __align__(16) unsigned short h_lds[16 * LDS_STRIDE];
    __shared__ __align__(16) unsigned short xp_lds[2][16 * LDS_STRIDE];
    __shared__ __align__(16) int tok_lds[16 * 128];
    __shared__ __align__(16) float wcls_lds[5 * 256];
    __shared__ float bcls_lds[5];

    const int tid   = threadIdx.x;
    const int lane  = tid & 63;
    const int wid   = tid >> 6;
    const int b0    = blockIdx.x * 16;   // 256 * 16 == 4096
    const int n0    = wid * 64;
    const int row16 = tid >> 4;          // loader: row 0..15
    const int seg   = tid & 15;          // loader: 16-bf16 (32B) segment

    // W_hh (f32) -> bf16 B-fragments, resident in VGPRs for the whole time loop
    bf16x8 wf[4][8];
    #pragma unroll
    for (int nt = 0; nt < 4; ++nt) {
        int n = n0 + nt * 16 + (lane & 15);
        #pragma unroll
        for (int kt = 0; kt < 8; ++kt) {
            int k = (lane >> 4) * 8 + kt * 32;
            wf[nt][kt] = pack8(W_hh + n * 256 + k);
        }
    }

    // All 2048 tokens for this block's 16 rows (int32)
    {
        const int4* xs = (const int4*)(x + (size_t)b0 * 128);
        ((int4*)tok_lds)[tid * 2]     = xs[tid * 2];
        ((int4*)tok_lds)[tid * 2 + 1] = xs[tid * 2 + 1];
    }
    for (int i = tid; i < 320; i += 256)
        ((float4*)wcls_lds)[i] = ((const float4*)W_cls)[i];
    if (tid < 5) bcls_lds[tid] = b_cls[tid];
    for (int i = tid; i < 16 * LDS_STRIDE / 2; i += 256) ((unsigned int*)h_lds)[i] = 0;

    // Prefetch xp for t=0 (from bf16 table g_P)
    {
        int tok = x[(size_t)(b0 + row16) * 128];
        tok = min(max(tok, 0), VOCAB - 1);
        const float4* src = (const float4*)(g_P + (size_t)tok * 256 + seg * 16);
        float4 a0 = src[0], a1 = src[1];
        *(float4*)(&xp_lds[0][row16 * LDS_STRIDE + seg * 16])     = a0;
        *(float4*)(&xp_lds[0][row16 * LDS_STRIDE + seg * 16 + 8]) = a1;
    }
    __syncthreads();

    for (int t = 0; t < 128; ++t) {
        const int buf = t & 1;

        // Issue next step's gather early (latency hidden behind MFMA + tanh)
        float4 p0, p1;
        const bool have = (t + 1) < 128;
        if (have) {
            int tok = tok_lds[row16 * 128 + t + 1];
            tok = min(max(tok, 0), VOCAB - 1);
            const float4* src = (const float4*)(g_P + (size_t)tok * 256 + seg * 16);
            p0 = src[0]; p1 = src[1];
        }

        f32x4 acc[4];
        #pragma unroll
        for (int nt = 0; nt < 4; ++nt) acc[nt] = (f32x4){0.f, 0.f, 0.f, 0.f};
        #pragma unroll
        for (int kt = 0; kt < 8; ++kt) {
            // A[m][k]: m = lane&15, k = (lane>>4)*8 + kt*32 + j -> contiguous 16B in h_lds
            bf16x8 a = *(bf16x8*)(&h_lds[(lane & 15) * LDS_STRIDE + (lane >> 4) * 8 + kt * 32]);
            #pragma unroll
            for (int nt = 0; nt < 4; ++nt)
                acc[nt] = __builtin_amdgcn_mfma_f32_16x16x32_bf16(a, wf[nt][kt], acc[nt], 0, 0, 0);
        }

        // Epilogue: add xp, tanh. All h_lds/xp_lds[buf] reads complete before barrier 1.
        float th[4][4];
        #pragma unroll
        for (int nt = 0; nt < 4; ++nt) {
            int col = n0 + nt * 16 + (lane & 15);
            #pragma unroll
            for (int r = 0; r < 4; ++r) {
                int rrow = (lane >> 4) * 4 + r;
                float v = acc[nt][r] + bf2f(xp_lds[buf][rrow * LDS_STRIDE + col]);
                th[nt][r] = tanhf(v);
            }
        }
        __syncthreads();   // barrier 1: everyone done reading h_lds + xp_lds[buf]

        #pragma unroll
        for (int nt = 0; nt < 4; ++nt) {
            int col = n0 + nt * 16 + (lane & 15);
            #pragma unroll
            for (int r = 0; r < 4; ++r) {
                int rrow = (lane >> 4) * 4 + r;
                h_lds[rrow * LDS_STRIDE + col] = f2bf(th[nt][r]);
            }
        }
        if (have) {
            *(float4*)(&xp_lds[buf ^ 1][row16 * LDS_STRIDE + seg * 16])     = p0;
            *(float4*)(&xp_lds[buf ^ 1][row16 * LDS_STRIDE + seg * 16 + 8]) = p1;
        }
        __syncthreads();   // barrier 2: new h + next xp visible
    }

    // Classifier: out[b][c] = h . W_cls[c] + b_cls[c]   (f32 out)
    if (tid < 80) {
        int row = tid / 5, c = tid % 5;
        float acc = bcls_lds[c];
        for (int k = 0; k < 256; ++k)
            acc += bf2f(h_lds[row * LDS_STRIDE + k]) * wcls_lds[c * 256 + k];
        out[(size_t)(b0 + row) * 5 + c] = acc;
    }
}

extern "C" void kernel_launch(void* const* d_in, const int* in_sizes, int n_in,
                              void* d_out, int out_size, void* d_ws, size_t ws_size,
                              hipStream_t stream)
{
    const int*   x     = (const int*)d_in[0];
    const float* emb   = (const float*)d_in[1];
    const float* W_ih  = (const float*)d_in[2];
    const float* W_hh  = (const float*)d_in[3];
    const float* b_ih  = (const float*)d_in[4];
    const float* b_hh  = (const float*)d_in[5];
    const float* W_cls = (const float*)d_in[6];
    const float* b_cls = (const float*)d_in[7];
    float*       out   = (float*)d_out;
    (void)d_ws; (void)ws_size;

    emb_proj_kernel<<<3125, 256, 0, stream>>>(emb, W_ih, b_ih, b_hh);
    rnn_kernel<<<256, 256, 0, stream>>>(x, W_hh, W_cls, b_cls, out);
}

// Round 4
// 235.904 us; speedup vs baseline: 2.1592x; 2.1592x over previous
//
#include <hip/hip_runtime.h>
#include <math.h>

// emb lookup -> RNN tanh(xp_t + h @ W_hh^T) over S=128 -> 5-class head.
// B=4096, S=128, D=256, VOCAB=50000. Floats are f32, x int32, out f32.
//
// Phase 0: P[v] = bf16(emb[v] @ W_ih^T + b_ih + b_hh) — project the 50k-row TABLE, not
//          524k tokens. Grid-stride tiles; W_ih fragments loaded once per block
//          (round-3 version reloaded W per tile with SCALAR loads -> 179 us).
// Phase 1: 256 blocks x 16 rows, 512 threads (8 waves, 2 waves/SIMD for latency hiding).
//          W_hh bf16 B-fragments in VGPRs; h double-buffered in LDS -> ONE barrier/step;
//          xp gathered from P one step ahead (double-buffered); fast tanh via v_exp_f32.

typedef __attribute__((ext_vector_type(8))) short bf16x8;   // 8 bf16 = 4 VGPRs
typedef __attribute__((ext_vector_type(4))) float f32x4;    // MFMA 16x16 accumulator

#define LDS_STRIDE 264   // 256 + 8 pad (bf16 elems)
#define VOCAB 50000

__device__ __align__(256) unsigned short g_P[VOCAB * 256];  // 25.6 MB projected table

static __device__ __forceinline__ float bf2f(unsigned short u) {
    union { unsigned int i; float f; } v; v.i = ((unsigned int)u) << 16; return v.f;
}
static __device__ __forceinline__ unsigned short f2bf(float f) {
    union { float f; unsigned int i; } v; v.f = f;
    unsigned int r = v.i + 0x7FFFu + ((v.i >> 16) & 1u);   // RNE
    return (unsigned short)(r >> 16);
}
// 8 consecutive f32 -> bf16x8, via two vector loads (NOT 8 scalar loads)
static __device__ __forceinline__ bf16x8 load8_bf(const float* __restrict__ p) {
    float4 a = ((const float4*)p)[0], b = ((const float4*)p)[1];
    bf16x8 r;
    r[0] = (short)f2bf(a.x); r[1] = (short)f2bf(a.y);
    r[2] = (short)f2bf(a.z); r[3] = (short)f2bf(a.w);
    r[4] = (short)f2bf(b.x); r[5] = (short)f2bf(b.y);
    r[6] = (short)f2bf(b.z); r[7] = (short)f2bf(b.w);
    return r;
}
// tanh(x) = 1 - 2/(e^{2x}+1): ~7 VALU insts vs ~40 for library tanhf.
static __device__ __forceinline__ float fast_tanh(float x) {
    x = fminf(8.f, fmaxf(-8.f, x));          // tanh(+-8)==+-1 to 2e-7; keeps exp finite
    float e = __expf(2.f * x);               // v_exp_f32
    return 1.f - 2.f * __builtin_amdgcn_rcpf(e + 1.f);
}

// ---------------- Phase 0: P = bf16(emb @ W_ih^T + (b_ih + b_hh)) ----------------
__global__ __launch_bounds__(256)
void emb_proj_kernel(const float* __restrict__ emb,
                     const float* __restrict__ W_ih,
                     const float* __restrict__ b_ih,
                     const float* __restrict__ b_hh)
{
    __shared__ __align__(16) unsigned short tin [16 * LDS_STRIDE];
    __shared__ __align__(16) unsigned short tout[16 * LDS_STRIDE];
    const int tid  = threadIdx.x;
    const int lane = tid & 63;
    const int wid  = tid >> 6;          // 4 waves
    const int n0   = wid * 64;
    const int row  = tid >> 4, seg = tid & 15;

    // W_ih -> bf16 B-fragments, ONCE per block: B[k][n]; n = lane&15, k = quad*8 + j
    bf16x8 wf[4][8];
    float  bias[4];
    #pragma unroll
    for (int nt = 0; nt < 4; ++nt) {
        int n = n0 + nt * 16 + (lane & 15);
        bias[nt] = b_ih[n] + b_hh[n];
        #pragma unroll
        for (int kt = 0; kt < 8; ++kt) {
            int k = (lane >> 4) * 8 + kt * 32;
            wf[nt][kt] = load8_bf(W_ih + n * 256 + k);
        }
    }

    for (int tile = blockIdx.x; tile < 3125; tile += gridDim.x) {
        const int v0 = tile * 16;
        // stage 16 emb rows (f32 -> bf16), vectorized
        {
            const float* src = emb + (size_t)(v0 + row) * 256 + seg * 16;
            bf16x8 lo = load8_bf(src), hi = load8_bf(src + 8);
            *(bf16x8*)(&tin[row * LDS_STRIDE + seg * 16])     = lo;
            *(bf16x8*)(&tin[row * LDS_STRIDE + seg * 16 + 8]) = hi;
        }
        __syncthreads();   // stage visible; also guards tout copy of prev iter vs epilogue below

        f32x4 acc[4];
        #pragma unroll
        for (int nt = 0; nt < 4; ++nt) acc[nt] = (f32x4){0.f, 0.f, 0.f, 0.f};
        #pragma unroll
        for (int kt = 0; kt < 8; ++kt) {
            bf16x8 a = *(bf16x8*)(&tin[(lane & 15) * LDS_STRIDE + (lane >> 4) * 8 + kt * 32]);
            #pragma unroll
            for (int nt = 0; nt < 4; ++nt)
                acc[nt] = __builtin_amdgcn_mfma_f32_16x16x32_bf16(a, wf[nt][kt], acc[nt], 0, 0, 0);
        }
        // C/D: col = lane&15, row = quad*4 + r  -> scatter into tout (separate buffer)
        #pragma unroll
        for (int nt = 0; nt < 4; ++nt) {
            int n = n0 + nt * 16 + (lane & 15);
            #pragma unroll
            for (int r = 0; r < 4; ++r)
                tout[((lane >> 4) * 4 + r) * LDS_STRIDE + n] = f2bf(acc[nt][r] + bias[nt]);
        }
        __syncthreads();   // tout complete; tin A-reads complete (safe to restage next iter)
        {
            uint4 a0 = *(uint4*)(&tout[row * LDS_STRIDE + seg * 16]);
            uint4 a1 = *(uint4*)(&tout[row * LDS_STRIDE + seg * 16 + 8]);
            uint4* dst = (uint4*)(g_P + (size_t)(v0 + row) * 256 + seg * 16);
            dst[0] = a0; dst[1] = a1;
        }
    }
}

// ---------------- Phase 1: recurrence + classifier ----------------
__global__ __launch_bounds__(512, 1)
void rnn_kernel(const int* __restrict__ x,
                const float* __restrict__ W_hh,
                const float* __restrict__ W_cls,
                const float* __restrict__ b_cls,
                float* __restrict__ out)
{
    __shared__ __align__(16) unsigned short h_lds [2][16 * LDS_STRIDE];
    __shared__ __align__(16) unsigned short xp_lds[2][16 * LDS_STRIDE];
    __shared__ __align__(16) int tok_lds[16 * 128];
    __shared__ __align__(16) float wcls_lds[5 * 256];
    __shared__ float bcls_lds[5];

    const int tid   = threadIdx.x;
    const int lane  = tid & 63;
    const int wid   = tid >> 6;          // 8 waves
    const int b0    = blockIdx.x * 16;   // 256 * 16 == 4096
    const int n0    = wid * 32;          // wave's 32-col slice (2 x 16)
    const int grow  = tid >> 5;          // gather: row 0..15
    const int gseg  = tid & 31;          // gather: 8-bf16 (16B) segment

    // W_hh -> bf16 B-fragments (2 nt x 8 kt), VGPR-resident all 128 steps
    bf16x8 wf[2][8];
    #pragma unroll
    for (int nt = 0; nt < 2; ++nt) {
        int n = n0 + nt * 16 + (lane & 15);
        #pragma unroll
        for (int kt = 0; kt < 8; ++kt) {
            int k = (lane >> 4) * 8 + kt * 32;
            wf[nt][kt] = load8_bf(W_hh + n * 256 + k);
        }
    }

    // stage all 2048 tokens, classifier weights, zero h buffer 0
    ((int4*)tok_lds)[tid] = ((const int4*)(x + (size_t)b0 * 128))[tid];
    if (tid < 320) ((float4*)wcls_lds)[tid] = ((const float4*)W_cls)[tid];
    if (tid < 5)   bcls_lds[tid] = b_cls[tid];
    for (int i = tid; i < 16 * LDS_STRIDE / 2; i += 512) ((unsigned int*)h_lds[0])[i] = 0;

    // prefetch xp for t=0
    {
        int tok = x[(size_t)(b0 + grow) * 128];
        tok = min(max(tok, 0), VOCAB - 1);
        float4 p = *(const float4*)(g_P + (size_t)tok * 256 + gseg * 8);
        *(float4*)(&xp_lds[0][grow * LDS_STRIDE + gseg * 8]) = p;
    }
    __syncthreads();

    for (int t = 0; t < 128; ++t) {
        const int buf = t & 1;           // h read buf == xp read buf

        // issue next step's gather early (one 16B load/thread; hidden behind MFMA+tanh)
        float4 p;
        const bool have = (t + 1) < 128;
        if (have) {
            int tok = tok_lds[grow * 128 + t + 1];
            tok = min(max(tok, 0), VOCAB - 1);
            p = *(const float4*)(g_P + (size_t)tok * 256 + gseg * 8);
        }

        f32x4 acc[2];
        acc[0] = (f32x4){0.f, 0.f, 0.f, 0.f};
        acc[1] = (f32x4){0.f, 0.f, 0.f, 0.f};
        #pragma unroll
        for (int kt = 0; kt < 8; ++kt) {
            bf16x8 a = *(bf16x8*)(&h_lds[buf][(lane & 15) * LDS_STRIDE + (lane >> 4) * 8 + kt * 32]);
            acc[0] = __builtin_amdgcn_mfma_f32_16x16x32_bf16(a, wf[0][kt], acc[0], 0, 0, 0);
            acc[1] = __builtin_amdgcn_mfma_f32_16x16x32_bf16(a, wf[1][kt], acc[1], 0, 0, 0);
        }

        // epilogue: + xp, tanh, write new h into the OTHER buffer (no barrier needed first)
        #pragma unroll
        for (int nt = 0; nt < 2; ++nt) {
            int col = n0 + nt * 16 + (lane & 15);
            #pragma unroll
            for (int r = 0; r < 4; ++r) {
                int rrow = (lane >> 4) * 4 + r;
                float v = acc[nt][r] + bf2f(xp_lds[buf][rrow * LDS_STRIDE + col]);
                h_lds[buf ^ 1][rrow * LDS_STRIDE + col] = f2bf(fast_tanh(v));
            }
        }
        if (have)
            *(float4*)(&xp_lds[buf ^ 1][grow * LDS_STRIDE + gseg * 8]) = p;
        __syncthreads();   // single barrier: everything for t done, t+1 buffers ready
    }

    // after t=127 (odd): final h is in h_lds[0]
    if (tid < 80) {
        int row = tid / 5, c = tid % 5;
        float acc = bcls_lds[c];
        for (int k = 0; k < 256; ++k)
            acc += bf2f(h_lds[0][row * LDS_STRIDE + k]) * wcls_lds[c * 256 + k];
        out[(size_t)(b0 + row) * 5 + c] = acc;
    }
}

extern "C" void kernel_launch(void* const* d_in, const int* in_sizes, int n_in,
                              void* d_out, int out_size, void* d_ws, size_t ws_size,
                              hipStream_t stream)
{
    const int*   x     = (const int*)d_in[0];
    const float* emb   = (const float*)d_in[1];
    const float* W_ih  = (const float*)d_in[2];
    const float* W_hh  = (const float*)d_in[3];
    const float* b_ih  = (const float*)d_in[4];
    const float* b_hh  = (const float*)d_in[5];
    const float* W_cls = (const float*)d_in[6];
    const float* b_cls = (const float*)d_in[7];
    float*       out   = (float*)d_out;
    (void)d_ws; (void)ws_size;

    emb_proj_kernel<<<512, 256, 0, stream>>>(emb, W_ih, b_ih, b_hh);
    rnn_kernel<<<256, 512, 0, stream>>>(x, W_hh, W_cls, b_cls, out);
}